// Round 9
// baseline (285.242 us; speedup 1.0000x reference)
//
#include <hip/hip_runtime.h>
#include <hip/hip_bf16.h>

// LightGCN propagation: x = concat(user,item) [150000,64] f32;
// acc = x; 3x { x = A@x (COO spmm, E=1.2M); acc += x }; out = acc/4.
//
// Pipeline (6 dispatches), padded-bucket CSR (NO histogram, NO global scan):
//  1) memset cursor1 (293 x 4B)
//  2) s1_convert (role-split grid): LDS-rank edges per bucket (row>>9),
//     reserve via atomicAdd(cursor1[b]), write 8B records tmp[b*CAP+pos];
//     + x0 fp32->fp16 staging.
//  3) scatter2: one 512-thr block per bucket; rank-atomics (register-cached),
//     LDS scan of 512 row counters -> rbeg/rend + placement into padded cw.
//  4-6) spmm x3: PERSISTENT grid-stride (2048 blocks = 32 waves/CU all
//     resident; round-8 ran 37.5K short-lived blocks per layer and was
//     wave-churn bound at ~48us/layer). 1 wave/row-iteration, 8 edge-groups
//     x 8 lanes x 16B fp16 gathers. Layer 3 fuses out = 0.25*(x0h+x1+x2+acc).
//
// NOTE (round 6 post-mortem): non-temporal hints REGRESSED spmm (61->72us):
// nt-storing Xout evicts exactly the lines the next layer's random gathers
// need from L2. Do not nt-store gather-consumed data.

#define EMB 64
#define BUCKET_SHIFT 9
#define BROWS (1 << BUCKET_SHIFT)
#define NBUCK_PAD 320
#define S1_CHUNK 2048
#define BCAP 4608
#define S2_CAP 12
#define SPMM_BLOCKS 2048

typedef _Float16 h8 __attribute__((ext_vector_type(8)));
typedef _Float16 h2v __attribute__((ext_vector_type(2)));
typedef float f2v __attribute__((ext_vector_type(2)));
typedef float f4 __attribute__((ext_vector_type(4)));
typedef int i2v __attribute__((ext_vector_type(2)));

union H8U { h8 v; h2v p[4]; };

// ---- fused scatter1 + fp32->fp16 convert (role-split grid) ----
__global__ void s1_convert(const int* __restrict__ row, const int* __restrict__ col,
                           const float* __restrict__ w, int* __restrict__ cursor1,
                           int2* __restrict__ tmp,
                           const float* __restrict__ ue, const float* __restrict__ ie,
                           h8* __restrict__ X0h, int nu_elems, int total8,
                           int E, int s1Blocks) {
    int t = threadIdx.x;
    if ((int)blockIdx.x < s1Blocks) {
        __shared__ int lcount[NBUCK_PAD];
        __shared__ int lbase[NBUCK_PAD];
        int c0 = blockIdx.x * S1_CHUNK;
        if (t < NBUCK_PAD) lcount[t] = 0;
        __syncthreads();
        int pkc[S1_CHUNK / 512];   // (b<<12)|rank
        int cc[S1_CHUNK / 512];
        int rr[S1_CHUNK / 512];
        float ww[S1_CHUNK / 512];
        #pragma unroll
        for (int i = 0; i < S1_CHUNK / 512; i++) {
            int e = c0 + i * 512 + t;
            pkc[i] = -1;
            if (e < E) {
                int r = row[e];
                int b = r >> BUCKET_SHIFT;
                int rank = atomicAdd(&lcount[b], 1);
                pkc[i] = (b << 12) | rank;
                cc[i] = col[e];
                rr[i] = r & (BROWS - 1);
                ww[i] = w[e];
            }
        }
        __syncthreads();
        if (t < NBUCK_PAD) {
            int c = lcount[t];
            if (c) lbase[t] = atomicAdd(&cursor1[t], c);
        }
        __syncthreads();
        #pragma unroll
        for (int i = 0; i < S1_CHUNK / 512; i++) {
            if (pkc[i] >= 0) {
                int b = pkc[i] >> 12;
                int pos = lbase[b] + (pkc[i] & 4095);
                if (pos < BCAP)   // overflow guard (never triggers at +8 sigma)
                    tmp[(size_t)b * BCAP + pos] =
                        make_int2((cc[i] << BUCKET_SHIFT) | rr[i], __float_as_int(ww[i]));
            }
        }
    } else {
        int g = (blockIdx.x - s1Blocks) * 512 + t;
        if (g >= total8) return;
        int base = g << 3;
        const f4* src = (const f4*)((base < nu_elems) ? (ue + base)
                                                      : (ie + (base - nu_elems)));
        f4 a = src[0], b = src[1];
        h8 o;
        o[0] = (_Float16)a.x; o[1] = (_Float16)a.y; o[2] = (_Float16)a.z; o[3] = (_Float16)a.w;
        o[4] = (_Float16)b.x; o[5] = (_Float16)b.y; o[6] = (_Float16)b.z; o[7] = (_Float16)b.w;
        X0h[g] = o;
    }
}

// ---- scatter2: rank + scan + place; writes rbeg/rend and padded cw ----
__global__ void scatter2(const int* __restrict__ cursor1, const int2* __restrict__ tmp,
                         int2* __restrict__ cw, int* __restrict__ rbeg,
                         int* __restrict__ rend, int nrows) {
    __shared__ int cnt[BROWS];
    __shared__ int wS[8];
    int t = threadIdx.x;
    int j = blockIdx.x;
    int rowbase = j << BUCKET_SHIFT;
    int rows_here = nrows - rowbase;
    if (rows_here > BROWS) rows_here = BROWS;
    int num = cursor1[j];
    if (num > BCAP) num = BCAP;
    int base = j * BCAP;
    int iters = (num + 511) >> 9;

    cnt[t] = 0;
    __syncthreads();

    int pkc[S2_CAP];
    int rk[S2_CAP];
    int wv[S2_CAP];
    bool cached = (iters <= S2_CAP);
    if (cached) {
        for (int i = 0; i < iters; i++) {
            int p = i * 512 + t;
            pkc[i] = -1;
            if (p < num) {
                int2 rec = tmp[base + p];
                pkc[i] = rec.x;
                wv[i] = rec.y;
                rk[i] = atomicAdd(&cnt[rec.x & (BROWS - 1)], 1);
            }
        }
    } else {
        for (int p = t; p < num; p += 512)
            atomicAdd(&cnt[tmp[base + p].x & (BROWS - 1)], 1);
    }
    __syncthreads();

    int v = cnt[t];
    int lane = t & 63;
    int wave = t >> 6;
    int s = v;
    #pragma unroll
    for (int off = 1; off < 64; off <<= 1) {
        int tt = __shfl_up(s, off, 64);
        if (lane >= off) s += tt;
    }
    if (lane == 63) wS[wave] = s;
    __syncthreads();
    int woff = 0;
    for (int w = 0; w < wave; w++) woff += wS[w];
    int excl = woff + s - v;
    if (t < rows_here) {
        rbeg[rowbase + t] = base + excl;
        rend[rowbase + t] = base + excl + v;
    }
    __syncthreads();
    cnt[t] = excl;
    __syncthreads();

    if (cached) {
        for (int i = 0; i < iters; i++) {
            if (pkc[i] >= 0) {
                int r = pkc[i] & (BROWS - 1);
                cw[base + cnt[r] + rk[i]] = make_int2(pkc[i] >> BUCKET_SHIFT, wv[i]);
            }
        }
    } else {
        for (int p = t; p < num; p += 512) {
            int2 rec = tmp[base + p];
            int r = rec.x & (BROWS - 1);
            int pos = atomicAdd(&cnt[r], 1);
            cw[base + pos] = make_int2(rec.x >> BUCKET_SHIFT, rec.y);
        }
    }
}

// ---- spmm: persistent grid-stride; 1 wave/row-iter; 8 groups x 8 lanes ----
// LAST fuses out = 0.25*(x0h + x1 + x2 + acc)
template <bool LAST>
__global__ __launch_bounds__(256) void spmm_kernel(
        const int* __restrict__ rbeg, const int* __restrict__ rend,
        const i2v* __restrict__ cw,
        const h8* __restrict__ Xin, h8* __restrict__ Xout,
        const h8* __restrict__ X0, const h8* __restrict__ X1,
        float* __restrict__ out, int nrows) {
    int lane = threadIdx.x & 63;
    int sub = lane >> 3;
    int l8 = lane & 7;
    int wv = (blockIdx.x * blockDim.x + threadIdx.x) >> 6;
    int totWaves = (gridDim.x * blockDim.x) >> 6;

    for (int wid = wv; wid < nrows; wid += totWaves) {
        int beg = rbeg[wid];
        int end = rend[wid];

        f2v acc2[4];
        #pragma unroll
        for (int k = 0; k < 4; k++) acc2[k] = (f2v){0.f, 0.f};

        int e = beg + sub;
        for (; e + 8 < end; e += 16) {
            i2v c0 = cw[e];
            i2v c1 = cw[e + 8];
            H8U v0, v1;
            v0.v = Xin[(c0.x << 3) + l8];
            v1.v = Xin[(c1.x << 3) + l8];
            float w0 = __int_as_float(c0.y);
            float w1 = __int_as_float(c1.y);
            f2v w0p = (f2v){w0, w0};
            f2v w1p = (f2v){w1, w1};
            #pragma unroll
            for (int k = 0; k < 4; k++) {
                acc2[k] += w0p * __builtin_convertvector(v0.p[k], f2v);
                acc2[k] += w1p * __builtin_convertvector(v1.p[k], f2v);
            }
        }
        if (e < end) {
            i2v c0 = cw[e];
            H8U v0;
            v0.v = Xin[(c0.x << 3) + l8];
            float w0 = __int_as_float(c0.y);
            f2v w0p = (f2v){w0, w0};
            #pragma unroll
            for (int k = 0; k < 4; k++)
                acc2[k] += w0p * __builtin_convertvector(v0.p[k], f2v);
        }

        float* a = (float*)acc2;
        #pragma unroll
        for (int k = 0; k < 8; k++) {
            a[k] += __shfl_xor(a[k], 8, 64);
            a[k] += __shfl_xor(a[k], 16, 64);
            a[k] += __shfl_xor(a[k], 32, 64);
        }

        if (sub == 0) {
            if (LAST) {
                h8 x0 = X0[(wid << 3) + l8];
                h8 v1 = X1[(wid << 3) + l8];
                h8 v2 = Xin[(wid << 3) + l8];
                int base = (wid << 6) + (l8 << 3);
                f4 o0, o1;
                o0.x = 0.25f * ((float)x0[0] + (float)v1[0] + (float)v2[0] + a[0]);
                o0.y = 0.25f * ((float)x0[1] + (float)v1[1] + (float)v2[1] + a[1]);
                o0.z = 0.25f * ((float)x0[2] + (float)v1[2] + (float)v2[2] + a[2]);
                o0.w = 0.25f * ((float)x0[3] + (float)v1[3] + (float)v2[3] + a[3]);
                o1.x = 0.25f * ((float)x0[4] + (float)v1[4] + (float)v2[4] + a[4]);
                o1.y = 0.25f * ((float)x0[5] + (float)v1[5] + (float)v2[5] + a[5]);
                o1.z = 0.25f * ((float)x0[6] + (float)v1[6] + (float)v2[6] + a[6]);
                o1.w = 0.25f * ((float)x0[7] + (float)v1[7] + (float)v2[7] + a[7]);
                f4* dst = (f4*)(out + base);
                dst[0] = o0;
                dst[1] = o1;
            } else {
                h8 o;
                #pragma unroll
                for (int k = 0; k < 8; k++) o[k] = (_Float16)a[k];
                Xout[(wid << 3) + l8] = o;
            }
        }
    }
}

extern "C" void kernel_launch(void* const* d_in, const int* in_sizes, int n_in,
                              void* d_out, int out_size, void* d_ws, size_t ws_size,
                              hipStream_t stream) {
    const int* edge_row = (const int*)d_in[0];
    const int* edge_col = (const int*)d_in[1];
    const float* edge_w = (const float*)d_in[2];
    const float* user_emb = (const float*)d_in[3];
    const float* item_emb = (const float*)d_in[4];

    const int E = in_sizes[0];
    const int nu_elems = in_sizes[3];
    const int ni_elems = in_sizes[4];
    const int total = nu_elems + ni_elems;
    const int N = total / EMB;                           // 150000
    const int NBUCK = (N + BROWS - 1) >> BUCKET_SHIFT;   // 293

    size_t off = 0;
    auto carve = [&](size_t bytes) {
        void* p = (char*)d_ws + off;
        off += (bytes + 255) & ~(size_t)255;
        return p;
    };
    h8*    X0h     = (h8*)carve((size_t)total * 2);
    h8*    X1h     = (h8*)carve((size_t)total * 2);
    h8*    X2h     = (h8*)carve((size_t)total * 2);
    int*   rbeg    = (int*)carve((size_t)N * 4);
    int*   rend    = (int*)carve((size_t)N * 4);
    int*   cursor1 = (int*)carve((size_t)NBUCK * 4);
    int2*  tmp     = (int2*)carve((size_t)NBUCK * BCAP * 8);
    int2*  cw      = (int2*)carve((size_t)NBUCK * BCAP * 8);
    (void)ws_size;

    float* out = (float*)d_out;

    const int total8 = total / 8;
    const int s1Blocks = (E + S1_CHUNK - 1) / S1_CHUNK;
    const int convBlocks = (total8 + 511) / 512;

    hipMemsetAsync(cursor1, 0, (size_t)NBUCK * 4, stream);
    s1_convert<<<s1Blocks + convBlocks, 512, 0, stream>>>(
        edge_row, edge_col, edge_w, cursor1, tmp,
        user_emb, item_emb, X0h, nu_elems, total8, E, s1Blocks);
    scatter2<<<NBUCK, 512, 0, stream>>>(cursor1, tmp, cw, rbeg, rend, N);

    spmm_kernel<false><<<SPMM_BLOCKS, 256, 0, stream>>>(rbeg, rend, (const i2v*)cw,
                                                        X0h, X1h, nullptr, nullptr,
                                                        nullptr, N);
    spmm_kernel<false><<<SPMM_BLOCKS, 256, 0, stream>>>(rbeg, rend, (const i2v*)cw,
                                                        X1h, X2h, nullptr, nullptr,
                                                        nullptr, N);
    spmm_kernel<true><<<SPMM_BLOCKS, 256, 0, stream>>>(rbeg, rend, (const i2v*)cw,
                                                       X2h, nullptr, X0h, X1h,
                                                       out, N);
}

// Round 10
// 229.373 us; speedup vs baseline: 1.2436x; 1.2436x over previous
//
#include <hip/hip_runtime.h>
#include <hip/hip_bf16.h>

// LightGCN propagation: x = concat(user,item) [150000,64] f32;
// acc = x; 3x { x = A@x (COO spmm, E=1.2M); acc += x }; out = acc/4.
//
// Pipeline (6 dispatches), padded-bucket CSR (NO histogram, NO global scan):
//  1) memset cursor1 (293 x 4B)
//  2) s1_convert (role-split grid): LDS-rank edges per bucket (row>>9),
//     reserve via atomicAdd(cursor1[b]), write 8B records tmp[b*CAP+pos];
//     + x0 fp32->fp16 staging.
//  3) scatter2: one 512-thr block per bucket; rank-atomics (register-cached),
//     LDS scan of 512 row counters -> rbeg/rend + placement into padded cw.
//  4-6) spmm x3: GROUP-PER-ROW: each 8-lane group owns one row (lane=16B
//     chunk), iterates its edges serially 2x-unrolled (16 gathers in
//     flight/wave). NO cross-group shuffle reduction (rounds<=9 spent 48
//     ops/row on it at avg degree 8 -> VALUBusy 45-50%), and the epilogue
//     runs at full 64-lane width (was 1/8). Layer 3 fuses
//     out = 0.25*(x0h+x1+x2+acc).
//
// NOTE (round 6 post-mortem): non-temporal hints REGRESSED spmm (61->72us):
// nt-storing Xout evicts exactly the lines the next layer's random gathers
// need from L2. Do not nt-store gather-consumed data.

#define EMB 64
#define BUCKET_SHIFT 9
#define BROWS (1 << BUCKET_SHIFT)
#define NBUCK_PAD 320
#define S1_CHUNK 2048
#define BCAP 4608
#define S2_CAP 12
#define SPMM_BLOCKS 2048

typedef _Float16 h8 __attribute__((ext_vector_type(8)));
typedef _Float16 h2v __attribute__((ext_vector_type(2)));
typedef float f2v __attribute__((ext_vector_type(2)));
typedef float f4 __attribute__((ext_vector_type(4)));
typedef int i2v __attribute__((ext_vector_type(2)));

union H8U { h8 v; h2v p[4]; };

// ---- fused scatter1 + fp32->fp16 convert (role-split grid) ----
__global__ void s1_convert(const int* __restrict__ row, const int* __restrict__ col,
                           const float* __restrict__ w, int* __restrict__ cursor1,
                           int2* __restrict__ tmp,
                           const float* __restrict__ ue, const float* __restrict__ ie,
                           h8* __restrict__ X0h, int nu_elems, int total8,
                           int E, int s1Blocks) {
    int t = threadIdx.x;
    if ((int)blockIdx.x < s1Blocks) {
        __shared__ int lcount[NBUCK_PAD];
        __shared__ int lbase[NBUCK_PAD];
        int c0 = blockIdx.x * S1_CHUNK;
        if (t < NBUCK_PAD) lcount[t] = 0;
        __syncthreads();
        int pkc[S1_CHUNK / 512];   // (b<<12)|rank
        int cc[S1_CHUNK / 512];
        int rr[S1_CHUNK / 512];
        float ww[S1_CHUNK / 512];
        #pragma unroll
        for (int i = 0; i < S1_CHUNK / 512; i++) {
            int e = c0 + i * 512 + t;
            pkc[i] = -1;
            if (e < E) {
                int r = row[e];
                int b = r >> BUCKET_SHIFT;
                int rank = atomicAdd(&lcount[b], 1);
                pkc[i] = (b << 12) | rank;
                cc[i] = col[e];
                rr[i] = r & (BROWS - 1);
                ww[i] = w[e];
            }
        }
        __syncthreads();
        if (t < NBUCK_PAD) {
            int c = lcount[t];
            if (c) lbase[t] = atomicAdd(&cursor1[t], c);
        }
        __syncthreads();
        #pragma unroll
        for (int i = 0; i < S1_CHUNK / 512; i++) {
            if (pkc[i] >= 0) {
                int b = pkc[i] >> 12;
                int pos = lbase[b] + (pkc[i] & 4095);
                if (pos < BCAP)   // overflow guard (never triggers at +8 sigma)
                    tmp[(size_t)b * BCAP + pos] =
                        make_int2((cc[i] << BUCKET_SHIFT) | rr[i], __float_as_int(ww[i]));
            }
        }
    } else {
        int g = (blockIdx.x - s1Blocks) * 512 + t;
        if (g >= total8) return;
        int base = g << 3;
        const f4* src = (const f4*)((base < nu_elems) ? (ue + base)
                                                      : (ie + (base - nu_elems)));
        f4 a = src[0], b = src[1];
        h8 o;
        o[0] = (_Float16)a.x; o[1] = (_Float16)a.y; o[2] = (_Float16)a.z; o[3] = (_Float16)a.w;
        o[4] = (_Float16)b.x; o[5] = (_Float16)b.y; o[6] = (_Float16)b.z; o[7] = (_Float16)b.w;
        X0h[g] = o;
    }
}

// ---- scatter2: rank + scan + place; writes rbeg/rend and padded cw ----
__global__ void scatter2(const int* __restrict__ cursor1, const int2* __restrict__ tmp,
                         int2* __restrict__ cw, int* __restrict__ rbeg,
                         int* __restrict__ rend, int nrows) {
    __shared__ int cnt[BROWS];
    __shared__ int wS[8];
    int t = threadIdx.x;
    int j = blockIdx.x;
    int rowbase = j << BUCKET_SHIFT;
    int rows_here = nrows - rowbase;
    if (rows_here > BROWS) rows_here = BROWS;
    int num = cursor1[j];
    if (num > BCAP) num = BCAP;
    int base = j * BCAP;
    int iters = (num + 511) >> 9;

    cnt[t] = 0;
    __syncthreads();

    int pkc[S2_CAP];
    int rk[S2_CAP];
    int wv[S2_CAP];
    bool cached = (iters <= S2_CAP);
    if (cached) {
        for (int i = 0; i < iters; i++) {
            int p = i * 512 + t;
            pkc[i] = -1;
            if (p < num) {
                int2 rec = tmp[base + p];
                pkc[i] = rec.x;
                wv[i] = rec.y;
                rk[i] = atomicAdd(&cnt[rec.x & (BROWS - 1)], 1);
            }
        }
    } else {
        for (int p = t; p < num; p += 512)
            atomicAdd(&cnt[tmp[base + p].x & (BROWS - 1)], 1);
    }
    __syncthreads();

    int v = cnt[t];
    int lane = t & 63;
    int wave = t >> 6;
    int s = v;
    #pragma unroll
    for (int off = 1; off < 64; off <<= 1) {
        int tt = __shfl_up(s, off, 64);
        if (lane >= off) s += tt;
    }
    if (lane == 63) wS[wave] = s;
    __syncthreads();
    int woff = 0;
    for (int w = 0; w < wave; w++) woff += wS[w];
    int excl = woff + s - v;
    if (t < rows_here) {
        rbeg[rowbase + t] = base + excl;
        rend[rowbase + t] = base + excl + v;
    }
    __syncthreads();
    cnt[t] = excl;
    __syncthreads();

    if (cached) {
        for (int i = 0; i < iters; i++) {
            if (pkc[i] >= 0) {
                int r = pkc[i] & (BROWS - 1);
                cw[base + cnt[r] + rk[i]] = make_int2(pkc[i] >> BUCKET_SHIFT, wv[i]);
            }
        }
    } else {
        for (int p = t; p < num; p += 512) {
            int2 rec = tmp[base + p];
            int r = rec.x & (BROWS - 1);
            int pos = atomicAdd(&cnt[r], 1);
            cw[base + pos] = make_int2(rec.x >> BUCKET_SHIFT, rec.y);
        }
    }
}

// ---- spmm: group-per-row; 8 rows/wave; lane = 16B chunk of its row ----
// LAST fuses out = 0.25*(x0h + x1 + x2 + acc)
template <bool LAST>
__global__ __launch_bounds__(256) void spmm_kernel(
        const int* __restrict__ rbeg, const int* __restrict__ rend,
        const i2v* __restrict__ cw,
        const h8* __restrict__ Xin, h8* __restrict__ Xout,
        const h8* __restrict__ X0, const h8* __restrict__ X1,
        float* __restrict__ out, int nrows) {
    int lane = threadIdx.x & 63;
    int g = lane >> 3;     // which row of the wave's octet
    int l8 = lane & 7;     // 16B dim-chunk within the row
    int wv = (blockIdx.x * blockDim.x + threadIdx.x) >> 6;
    int totWaves = (gridDim.x * blockDim.x) >> 6;

    for (int base8 = wv * 8; base8 < nrows; base8 += totWaves * 8) {
        int row = base8 + g;
        bool valid = row < nrows;
        int beg = valid ? rbeg[row] : 0;
        int end = valid ? rend[row] : 0;

        f2v acc2[4];
        #pragma unroll
        for (int k = 0; k < 4; k++) acc2[k] = (f2v){0.f, 0.f};

        int e = beg;
        for (; e + 1 < end; e += 2) {
            i2v c0 = cw[e];
            i2v c1 = cw[e + 1];
            H8U v0, v1;
            v0.v = Xin[(c0.x << 3) + l8];
            v1.v = Xin[(c1.x << 3) + l8];
            float w0 = __int_as_float(c0.y);
            float w1 = __int_as_float(c1.y);
            f2v w0p = (f2v){w0, w0};
            f2v w1p = (f2v){w1, w1};
            #pragma unroll
            for (int k = 0; k < 4; k++) {
                acc2[k] += w0p * __builtin_convertvector(v0.p[k], f2v);
                acc2[k] += w1p * __builtin_convertvector(v1.p[k], f2v);
            }
        }
        if (e < end) {
            i2v c0 = cw[e];
            H8U v0;
            v0.v = Xin[(c0.x << 3) + l8];
            float w0 = __int_as_float(c0.y);
            f2v w0p = (f2v){w0, w0};
            #pragma unroll
            for (int k = 0; k < 4; k++)
                acc2[k] += w0p * __builtin_convertvector(v0.p[k], f2v);
        }

        float* a = (float*)acc2;
        if (valid) {
            if (LAST) {
                h8 x0 = X0[(row << 3) + l8];
                h8 v1 = X1[(row << 3) + l8];
                h8 v2 = Xin[(row << 3) + l8];
                int base = (row << 6) + (l8 << 3);
                f4 o0, o1;
                o0.x = 0.25f * ((float)x0[0] + (float)v1[0] + (float)v2[0] + a[0]);
                o0.y = 0.25f * ((float)x0[1] + (float)v1[1] + (float)v2[1] + a[1]);
                o0.z = 0.25f * ((float)x0[2] + (float)v1[2] + (float)v2[2] + a[2]);
                o0.w = 0.25f * ((float)x0[3] + (float)v1[3] + (float)v2[3] + a[3]);
                o1.x = 0.25f * ((float)x0[4] + (float)v1[4] + (float)v2[4] + a[4]);
                o1.y = 0.25f * ((float)x0[5] + (float)v1[5] + (float)v2[5] + a[5]);
                o1.z = 0.25f * ((float)x0[6] + (float)v1[6] + (float)v2[6] + a[6]);
                o1.w = 0.25f * ((float)x0[7] + (float)v1[7] + (float)v2[7] + a[7]);
                f4* dst = (f4*)(out + base);
                dst[0] = o0;
                dst[1] = o1;
            } else {
                h8 o;
                #pragma unroll
                for (int k = 0; k < 8; k++) o[k] = (_Float16)a[k];
                Xout[(row << 3) + l8] = o;
            }
        }
    }
}

extern "C" void kernel_launch(void* const* d_in, const int* in_sizes, int n_in,
                              void* d_out, int out_size, void* d_ws, size_t ws_size,
                              hipStream_t stream) {
    const int* edge_row = (const int*)d_in[0];
    const int* edge_col = (const int*)d_in[1];
    const float* edge_w = (const float*)d_in[2];
    const float* user_emb = (const float*)d_in[3];
    const float* item_emb = (const float*)d_in[4];

    const int E = in_sizes[0];
    const int nu_elems = in_sizes[3];
    const int ni_elems = in_sizes[4];
    const int total = nu_elems + ni_elems;
    const int N = total / EMB;                           // 150000
    const int NBUCK = (N + BROWS - 1) >> BUCKET_SHIFT;   // 293

    size_t off = 0;
    auto carve = [&](size_t bytes) {
        void* p = (char*)d_ws + off;
        off += (bytes + 255) & ~(size_t)255;
        return p;
    };
    h8*    X0h     = (h8*)carve((size_t)total * 2);
    h8*    X1h     = (h8*)carve((size_t)total * 2);
    h8*    X2h     = (h8*)carve((size_t)total * 2);
    int*   rbeg    = (int*)carve((size_t)N * 4);
    int*   rend    = (int*)carve((size_t)N * 4);
    int*   cursor1 = (int*)carve((size_t)NBUCK * 4);
    int2*  tmp     = (int2*)carve((size_t)NBUCK * BCAP * 8);
    int2*  cw      = (int2*)carve((size_t)NBUCK * BCAP * 8);
    (void)ws_size;

    float* out = (float*)d_out;

    const int total8 = total / 8;
    const int s1Blocks = (E + S1_CHUNK - 1) / S1_CHUNK;
    const int convBlocks = (total8 + 511) / 512;

    hipMemsetAsync(cursor1, 0, (size_t)NBUCK * 4, stream);
    s1_convert<<<s1Blocks + convBlocks, 512, 0, stream>>>(
        edge_row, edge_col, edge_w, cursor1, tmp,
        user_emb, item_emb, X0h, nu_elems, total8, E, s1Blocks);
    scatter2<<<NBUCK, 512, 0, stream>>>(cursor1, tmp, cw, rbeg, rend, N);

    spmm_kernel<false><<<SPMM_BLOCKS, 256, 0, stream>>>(rbeg, rend, (const i2v*)cw,
                                                        X0h, X1h, nullptr, nullptr,
                                                        nullptr, N);
    spmm_kernel<false><<<SPMM_BLOCKS, 256, 0, stream>>>(rbeg, rend, (const i2v*)cw,
                                                        X1h, X2h, nullptr, nullptr,
                                                        nullptr, N);
    spmm_kernel<true><<<SPMM_BLOCKS, 256, 0, stream>>>(rbeg, rend, (const i2v*)cw,
                                                       X2h, nullptr, X0h, X1h,
                                                       out, N);
}